// Round 1
// baseline (630.862 us; speedup 1.0000x reference)
//
#include <hip/hip_runtime.h>
#include <cstdint>
#include <cstddef>

#define B_    4
#define N_    10000
#define E_    320000
#define FN_   16
#define INDIM 33
#define EH    64
#define EH2   32
#define EOUT  64
#define NHID  12

__device__ __forceinline__ float f4get(const float4& v, int k) {
    switch (k) { case 0: return v.x; case 1: return v.y; case 2: return v.z; default: return v.w; }
}
__device__ __forceinline__ void fma4(float4& a, float s, const float4 w) {
    a.x = fmaf(s, w.x, a.x); a.y = fmaf(s, w.y, a.y);
    a.z = fmaf(s, w.z, a.z); a.w = fmaf(s, w.w, a.w);
}
__device__ __forceinline__ void relu4(float4& a) {
    a.x = fmaxf(a.x, 0.f); a.y = fmaxf(a.y, 0.f);
    a.z = fmaxf(a.z, 0.f); a.w = fmaxf(a.w, 0.f);
}

// One block = 256 threads = 4 waves; each thread owns one edge of one batch.
// Layers 1-2 per-thread (weights broadcast from LDS); layer 3 transposed
// (lane = output channel) so the scatter atomics are lane-consecutive.
__global__ __launch_bounds__(256, 2) void edge_kernel(
    const float* __restrict__ nf,     // [B][N][16]
    const float* __restrict__ ew,     // [B][E]
    const int*   __restrict__ esrc,   // [E]
    const int*   __restrict__ etgt,   // [E]
    const float* __restrict__ W1, const float* __restrict__ b1,
    const float* __restrict__ W2, const float* __restrict__ b2,
    const float* __restrict__ W3, const float* __restrict__ b3,
    float* __restrict__ agg)          // [B][N][64]
{
    __shared__ float sW1[INDIM * EH];     // 8448 B
    __shared__ float sb1[EH];
    __shared__ float sW2[EH * EH2];       // 8192 B
    __shared__ float sb2[EH2];
    __shared__ float sh2[4][64][36];      // 36864 B, 144B row stride (16B aligned, bank-balanced)
    __shared__ int   sidx[4][64][2];      // 2048 B

    const int tid = threadIdx.x;
    const int b   = blockIdx.y;

    for (int i = tid; i < INDIM * EH; i += 256) sW1[i] = W1[i];
    for (int i = tid; i < EH * EH2;   i += 256) sW2[i] = W2[i];
    if (tid < EH)  sb1[tid] = b1[tid];
    if (tid < EH2) sb2[tid] = b2[tid];

    const int e   = blockIdx.x * 256 + tid;
    const int src = esrc[e];
    const int tgt = etgt[e];
    const float w = ew[(size_t)b * E_ + e];

    float4 inv[8];
    {
        const float4* ps = (const float4*)(nf + ((size_t)b * N_ + src) * FN_);
        const float4* pt = (const float4*)(nf + ((size_t)b * N_ + tgt) * FN_);
        inv[0] = ps[0]; inv[1] = ps[1]; inv[2] = ps[2]; inv[3] = ps[3];
        inv[4] = pt[0]; inv[5] = pt[1]; inv[6] = pt[2]; inv[7] = pt[3];
    }

    __syncthreads();   // weights staged

    // ---- layer 1: 33 -> 64, relu ----
    float4 h1[16];
    {
        const float4* bv = (const float4*)sb1;
        #pragma unroll
        for (int j = 0; j < 16; j++) h1[j] = bv[j];
    }
    #pragma unroll
    for (int i = 0; i < 32; i++) {
        float v = f4get(inv[i >> 2], i & 3);
        const float4* wr = (const float4*)(sW1 + i * EH);
        #pragma unroll
        for (int j = 0; j < 16; j++) fma4(h1[j], v, wr[j]);
    }
    {
        const float4* wr = (const float4*)(sW1 + 32 * EH);
        #pragma unroll
        for (int j = 0; j < 16; j++) fma4(h1[j], w, wr[j]);
    }
    #pragma unroll
    for (int j = 0; j < 16; j++) relu4(h1[j]);

    // ---- layer 2: 64 -> 32, relu ----
    float4 h2[8];
    {
        const float4* bv = (const float4*)sb2;
        #pragma unroll
        for (int j = 0; j < 8; j++) h2[j] = bv[j];
    }
    #pragma unroll
    for (int i = 0; i < 64; i++) {
        float v = f4get(h1[i >> 2], i & 3);
        const float4* wr = (const float4*)(sW2 + i * EH2);
        #pragma unroll
        for (int j = 0; j < 8; j++) fma4(h2[j], v, wr[j]);
    }
    #pragma unroll
    for (int j = 0; j < 8; j++) relu4(h2[j]);

    const int wv = tid >> 6, ln = tid & 63;
    {
        float4* dst = (float4*)&sh2[wv][ln][0];
        #pragma unroll
        for (int j = 0; j < 8; j++) dst[j] = h2[j];
        sidx[wv][ln][0] = src;
        sidx[wv][ln][1] = tgt;
    }

    // preload W3 column `ln` (stride-64 rows -> coalesced across lanes)
    float w3c[32];
    #pragma unroll
    for (int i = 0; i < 32; i++) w3c[i] = W3[i * EOUT + ln];
    const float bias3 = b3[ln];

    __syncthreads();   // h2 + indices staged

    // ---- layer 3 (transposed): 32 -> 64, sigmoid, signed scatter ----
    float* aggB = agg + (size_t)b * N_ * EOUT;
    for (int ee = 0; ee < 64; ee++) {
        const float4* hp = (const float4*)&sh2[wv][ee][0];   // broadcast reads
        float acc = bias3;
        #pragma unroll
        for (int c = 0; c < 8; c++) {
            float4 hh = hp[c];
            acc = fmaf(hh.x, w3c[4 * c + 0], acc);
            acc = fmaf(hh.y, w3c[4 * c + 1], acc);
            acc = fmaf(hh.z, w3c[4 * c + 2], acc);
            acc = fmaf(hh.w, w3c[4 * c + 3], acc);
        }
        float s = 1.0f / (1.0f + __expf(-acc));
        int t2 = sidx[wv][ee][1];
        int s2 = sidx[wv][ee][0];
        atomicAdd(aggB + (size_t)t2 * EOUT + ln,  s);   // 64 consecutive floats / wave instr
        atomicAdd(aggB + (size_t)s2 * EOUT + ln, -s);
    }
}

// One thread per (b, node): 65 -> 12 -> 1
__global__ __launch_bounds__(256) void node_kernel(
    const float* __restrict__ agg,    // [B*N][64]
    const float* __restrict__ lp,     // [B*N]
    const float* __restrict__ W4, const float* __restrict__ b4,
    const float* __restrict__ W5, const float* __restrict__ b5,
    float* __restrict__ out)          // [B*N]
{
    __shared__ float sW4[65 * NHID];
    __shared__ float sb4[NHID];
    __shared__ float sW5[NHID];
    __shared__ float sb5;

    const int tid = threadIdx.x;
    for (int i = tid; i < 65 * NHID; i += 256) sW4[i] = W4[i];
    if (tid < NHID) { sb4[tid] = b4[tid]; sW5[tid] = W5[tid]; }
    if (tid == 0) sb5 = b5[0];
    __syncthreads();

    const int idx = blockIdx.x * 256 + tid;
    if (idx >= B_ * N_) return;

    float nh[NHID];
    #pragma unroll
    for (int j = 0; j < NHID; j++) nh[j] = sb4[j];

    const float4* ar = (const float4*)(agg + (size_t)idx * EOUT);
    #pragma unroll
    for (int c = 0; c < 16; c++) {
        float4 a4 = ar[c];
        #pragma unroll
        for (int k = 0; k < 4; k++) {
            float v = f4get(a4, k);
            const float* wr = sW4 + (c * 4 + k) * NHID;
            #pragma unroll
            for (int j = 0; j < NHID; j++) nh[j] = fmaf(v, wr[j], nh[j]);
        }
    }
    {
        float v = lp[idx];
        const float* wr = sW4 + 64 * NHID;
        #pragma unroll
        for (int j = 0; j < NHID; j++) nh[j] = fmaf(v, wr[j], nh[j]);
    }

    float acc = sb5;
    #pragma unroll
    for (int j = 0; j < NHID; j++) acc = fmaf(fmaxf(nh[j], 0.f), sW5[j], acc);
    out[idx] = 1.0f / (1.0f + __expf(-acc));
}

extern "C" void kernel_launch(void* const* d_in, const int* in_sizes, int n_in,
                              void* d_out, int out_size, void* d_ws, size_t ws_size,
                              hipStream_t stream)
{
    const float* nf   = (const float*)d_in[0];
    const float* ew   = (const float*)d_in[1];
    const float* lp   = (const float*)d_in[2];
    const int*   esrc = (const int*)d_in[3];
    const int*   etgt = (const int*)d_in[4];
    const float* W1 = (const float*)d_in[5],  *b1 = (const float*)d_in[6];
    const float* W2 = (const float*)d_in[7],  *b2 = (const float*)d_in[8];
    const float* W3 = (const float*)d_in[9],  *b3 = (const float*)d_in[10];
    const float* W4 = (const float*)d_in[11], *b4 = (const float*)d_in[12];
    const float* W5 = (const float*)d_in[13], *b5 = (const float*)d_in[14];

    float* out = (float*)d_out;
    float* agg = (float*)d_ws;

    const size_t aggBytes = (size_t)B_ * N_ * EOUT * sizeof(float);
    hipMemsetAsync(agg, 0, aggBytes, stream);

    dim3 eg(E_ / 256, B_);
    edge_kernel<<<eg, 256, 0, stream>>>(nf, ew, esrc, etgt,
                                        W1, b1, W2, b2, W3, b3, agg);

    node_kernel<<<(B_ * N_ + 255) / 256, 256, 0, stream>>>(agg, lp, W4, b4, W5, b5, out);
}